// Round 11
// baseline (4318.438 us; speedup 1.0000x reference)
//
#include <hip/hip_runtime.h>
#include <math.h>

// ---------------------------------------------------------------------------
// Sizes
// ---------------------------------------------------------------------------
#define NB   512
#define TT   60
#define FF   5
#define HH   128
#define G4   512
#define NN   2500
#define KK   50

#define O0 800
#define O1 1500
#define O2 2100

// ---------------------------------------------------------------------------
// Workspace layout (float offsets).
// B-frag order (validated R6), now keyed by (cb, w, kb):
//   halfidx = ((cb*8 + w)*KBn + kb)*512 + l*8 + j
//   k = kb*32 + (l>>4)*8 + j ;  n = (w>>1)*128 + cb*32 + (w&1)*16 + (l&15)
// h chunk layout: [buf(2)][layer(2)][group(32)] of 16 rows x 128 k halves.
// ---------------------------------------------------------------------------
#define OFF_B0F   0                        // 81920 halves = 40960 floats
#define OFF_B1F   40960                    // 131072 halves = 65536 floats
#define OFF_BIAS0 106496                   // 512
#define OFF_BIAS1 107008                   // 512
#define OFF_A     107520                   // 2500
#define OFF_FS    110020                   // 512
#define OFF_FLAGS 110532                   // 32 ints
#define OFF_HBUF  110564                   // 131072 floats = 262144 halves
#define OFF_NO    241636                   // 512*2500
#define OFF_MEANS 1521636                  // 2048
#define OFF_H1    1523684                  // 512*256

#define P0 81920                           // end B0F (halves)
#define P1 212992                          // end B1F
#define P2 213504                          // end bias0
#define P3 214016                          // end bias1
#define P4 216516                          // end a[n]
#define P5 347588                          // end hbuf zero (floats)
#define PREP_TOTAL 347620                  // end flags zero

typedef _Float16 f16x8 __attribute__((ext_vector_type(8)));
typedef float f32x4 __attribute__((ext_vector_type(4)));

#define MFMA16(A, B, C) __builtin_amdgcn_mfma_f32_16x16x32_f16((A), (B), (C), 0, 0, 0)

__device__ __forceinline__ float sigf(float x) {
    return 1.0f / (1.0f + __expf(-x));
}
__device__ __forceinline__ float tanh2(float x) {
    float e = __expf(-2.0f * x);
    return fmaf(2.0f, 1.0f / (1.0f + e), -1.0f);
}

// 4-block group barrier through device-scope atomics.
__device__ __forceinline__ void group_sync(int* flag, int target) {
    __threadfence();                   // release: my h stores device-visible
    __syncthreads();                   // every thread's fence done
    if (threadIdx.x == 0) {
        atomicAdd(flag, 1);
        while (atomicAdd(flag, 0) < target) __builtin_amdgcn_s_sleep(1);
    }
    __syncthreads();
    __threadfence();                   // acquire: drop stale lines
}

// ---------------------------------------------------------------------------
// K0: prep — col-block-keyed B-frags, bias folds, a[n], zero hbuf + flags
// ---------------------------------------------------------------------------
__global__ __launch_bounds__(256) void prep_kernel(
    const float* __restrict__ W_ih0, const float* __restrict__ W_hh0,
    const float* __restrict__ b_ih0, const float* __restrict__ b_hh0,
    const float* __restrict__ W_ih1, const float* __restrict__ W_hh1,
    const float* __restrict__ b_ih1, const float* __restrict__ b_hh1,
    const float* __restrict__ conn_w, const float* __restrict__ sens,
    float* __restrict__ ws)
{
    int i = blockIdx.x * 256 + threadIdx.x;
    if (i >= PREP_TOTAL) return;

    if (i < P0) {                          // L0 B-frags (K=160 padded)
        int j = i & 7, l = (i >> 3) & 63;
        int rest = i >> 9;                 // 0..159
        int kb = rest % 5, t2 = rest / 5;
        int w = t2 & 7, cb = t2 >> 3;
        int k = kb * 32 + (l >> 4) * 8 + j;
        int n = (w >> 1) * 128 + cb * 32 + (w & 1) * 16 + (l & 15);
        float val = 0.f;
        if (k < 128)       val = W_hh0[n * HH + k];
        else if (k < 133)  val = W_ih0[n * FF + (k - 128)];
        ((_Float16*)(ws + OFF_B0F))[i] = (_Float16)val;
    } else if (i < P1) {                   // L1 B-frags (K=256)
        int v = i - P0;
        int j = v & 7, l = (v >> 3) & 63;
        int rest = v >> 9;                 // 0..255
        int kb = rest & 7, t2 = rest >> 3;
        int w = t2 & 7, cb = t2 >> 3;
        int k = kb * 32 + (l >> 4) * 8 + j;
        int n = (w >> 1) * 128 + cb * 32 + (w & 1) * 16 + (l & 15);
        float val = (k < 128) ? W_ih1[n * HH + k] : W_hh1[n * HH + (k - 128)];
        ((_Float16*)(ws + OFF_B1F))[v] = (_Float16)val;
    } else if (i < P2) {
        int j = i - P1;
        ws[OFF_BIAS0 + j] = b_ih0[j] + b_hh0[j];
    } else if (i < P3) {
        int j = i - P2;
        ws[OFF_BIAS1 + j] = b_ih1[j] + b_hh1[j];
    } else if (i < P4) {
        int n = i - P3;
        float s = 0.f;
        const float* cw = conn_w + n * KK;
        for (int k = 0; k < KK; ++k) s += cw[k];
        ws[OFF_A + n] = s * sens[n];
    } else if (i < P5) {                   // zero h buffers
        ws[OFF_HBUF + (i - P4)] = 0.f;
    } else {                               // zero group flags
        *((int*)(ws + OFF_FLAGS) + (i - P5)) = 0;
    }
}

// ---------------------------------------------------------------------------
// K1: distributed MFMA LSTM.  128 blocks x 512 threads.
// Block (g, cb): group g (16 batch rows), col-block cb (32 u's x 4 gates).
// Weight slice = 13 B-frags = 52 VGPR, REGISTER-RESIDENT (fits 128-VGPR cap).
// h exchanged between the group's 4 blocks via ws (double-buffered) with
// flag sync (2/step).  blockIdx mapped so a group shares an XCD.
// ---------------------------------------------------------------------------
__global__ __launch_bounds__(512) void lstm_mfma(
    const float* __restrict__ x,
    float* __restrict__ ws,
    const float* __restrict__ fp_w1, const float* __restrict__ fp_b1,
    const float* __restrict__ fp_w2, const float* __restrict__ fp_b2,
    float* __restrict__ feat_sum)
{
    __shared__ float gl[8 * 256];          // gate C-tiles [wave][row*16+col]
    __shared__ _Float16 xsh[16][304];
    __shared__ float t1s[16][65];
    __shared__ float bss[16][33];

    const int tid = threadIdx.x;
    const int w = tid >> 6, l = tid & 63;
    const int bid = blockIdx.x;
    const int xcd = bid & 7, slot = bid >> 3;
    const int g  = xcd + 8 * (slot >> 2);  // 32 groups
    const int cb = slot & 3;               // 4 col-blocks, same XCD per group

    _Float16* hb = (_Float16*)(ws + OFF_HBUF);
    int* flagp = (int*)(ws + OFF_FLAGS) + g;

    // wave's gate-column (per lane) and C-tile row base
    const int ncol = (w >> 1) * 128 + cb * 32 + (w & 1) * 16 + (l & 15);
    const int row0 = (l >> 4) * 4;
    // update-cell mapping: thread -> (batch row r, local unit uu)
    const int r = tid >> 5, uu = tid & 31;
    const int glupd = r * 16 + (uu & 15);
    const int wq0 = (uu >> 4);             // + 2*gate

    // stage x rows for this group
    for (int i = tid; i < 16 * TT * FF; i += 512) {
        int rr = i / 300, c = i % 300;
        xsh[rr][c] = (_Float16)x[(g * 16 + rr) * 300 + c];
    }

    const float bc0 = ws[OFF_BIAS0 + ncol];
    const float bc1 = ws[OFF_BIAS1 + ncol];
    float c0 = 0.f, c1 = 0.f;

    // ---- register-resident weight slice: 13 frags = 52 VGPR ----
    const f16x8* B0p = (const f16x8*)(ws + OFF_B0F) + ((cb * 8 + w) * 5) * 64 + l;
    const f16x8* B1p = (const f16x8*)(ws + OFF_B1F) + ((cb * 8 + w) * 8) * 64 + l;
    f16x8 wA0 = B0p[0],   wA1 = B0p[64],  wA2 = B0p[128], wA3 = B0p[192], wA4 = B0p[256];
    f16x8 wB0 = B1p[0],   wB1 = B1p[64],  wB2 = B1p[128], wB3 = B1p[192];
    f16x8 wB4 = B1p[256], wB5 = B1p[320], wB6 = B1p[384], wB7 = B1p[448];

    const int aoff = (l & 15) * 128 + (l >> 4) * 8;   // A-frag base (halves)
    const int hst  = r * 128 + cb * 32 + uu;          // h store offset

    int target = 0;
    __syncthreads();

    for (int t = 0; t < TT; ++t) {
        const int rb = t & 1, wbuf = rb ^ 1;

        // ---------- layer 0: gates = [h0_old | x] @ W0slice ----------
        const _Float16* h0r = hb + (((rb * 2 + 0) * 32 + g) << 11);
        f32x4 a = {bc0, bc0, bc0, bc0};
        f16x8 af;
        af = *(const f16x8*)(h0r + aoff +  0); a = MFMA16(af, wA0, a);
        af = *(const f16x8*)(h0r + aoff + 32); a = MFMA16(af, wA1, a);
        af = *(const f16x8*)(h0r + aoff + 64); a = MFMA16(af, wA2, a);
        af = *(const f16x8*)(h0r + aoff + 96); a = MFMA16(af, wA3, a);
        f16x8 xf = {(_Float16)0,(_Float16)0,(_Float16)0,(_Float16)0,
                    (_Float16)0,(_Float16)0,(_Float16)0,(_Float16)0};
        if (l < 16) {
            const _Float16* xr = &xsh[l][t * FF];
            xf[0]=xr[0]; xf[1]=xr[1]; xf[2]=xr[2]; xf[3]=xr[3]; xf[4]=xr[4];
        }
        a = MFMA16(xf, wA4, a);

#pragma unroll
        for (int q = 0; q < 4; ++q) gl[w * 256 + (row0 + q) * 16 + (l & 15)] = a[q];
        __syncthreads();
        {
            float vi = gl[(0 + wq0) * 256 + glupd];
            float vf = gl[(2 + wq0) * 256 + glupd];
            float vg = gl[(4 + wq0) * 256 + glupd];
            float vo = gl[(6 + wq0) * 256 + glupd];
            c0 = sigf(vf) * c0 + sigf(vi) * tanh2(vg);
            hb[(((wbuf * 2 + 0) * 32 + g) << 11) + hst] = (_Float16)(sigf(vo) * tanh2(c0));
        }
        target += 4;
        group_sync(flagp, target);          // h0(t) complete across col-blocks

        // ---------- layer 1: gates = [h0_new | h1_old] @ W1slice ----------
        const _Float16* h0n = hb + (((wbuf * 2 + 0) * 32 + g) << 11);
        const _Float16* h1r = hb + (((rb   * 2 + 1) * 32 + g) << 11);
        f32x4 b = {bc1, bc1, bc1, bc1};
        af = *(const f16x8*)(h0n + aoff +  0); b = MFMA16(af, wB0, b);
        af = *(const f16x8*)(h0n + aoff + 32); b = MFMA16(af, wB1, b);
        af = *(const f16x8*)(h0n + aoff + 64); b = MFMA16(af, wB2, b);
        af = *(const f16x8*)(h0n + aoff + 96); b = MFMA16(af, wB3, b);
        af = *(const f16x8*)(h1r + aoff +  0); b = MFMA16(af, wB4, b);
        af = *(const f16x8*)(h1r + aoff + 32); b = MFMA16(af, wB5, b);
        af = *(const f16x8*)(h1r + aoff + 64); b = MFMA16(af, wB6, b);
        af = *(const f16x8*)(h1r + aoff + 96); b = MFMA16(af, wB7, b);

#pragma unroll
        for (int q = 0; q < 4; ++q) gl[w * 256 + (row0 + q) * 16 + (l & 15)] = b[q];
        __syncthreads();
        {
            float vi = gl[(0 + wq0) * 256 + glupd];
            float vf = gl[(2 + wq0) * 256 + glupd];
            float vg = gl[(4 + wq0) * 256 + glupd];
            float vo = gl[(6 + wq0) * 256 + glupd];
            c1 = sigf(vf) * c1 + sigf(vi) * tanh2(vg);
            hb[(((wbuf * 2 + 1) * 32 + g) << 11) + hst] = (_Float16)(sigf(vo) * tanh2(c1));
        }
        target += 4;
        group_sync(flagp, target);          // h1(t) complete
    }

    // ---------- head MLP (col-block 0 only); final h1 in buf0 ----------
    if (cb != 0) return;
    const _Float16* h1f = hb + (((0 * 2 + 1) * 32 + g) << 11);
    for (int idx = tid; idx < 16 * 64; idx += 512) {
        int rr = idx >> 6, m = idx & 63;
        float acc = fp_b1[m];
        const float* wp = fp_w1 + m * HH;
        for (int k = 0; k < HH; ++k)
            acc = fmaf(wp[k], (float)h1f[rr * 128 + k], acc);
        t1s[rr][m] = fmaxf(acc, 0.f);
    }
    __syncthreads();
    {
        int rr = tid >> 5, q = tid & 31;    // 512 = 16*32
        float acc = fp_b2[q];
        const float* wp = fp_w2 + q * 64;
        for (int m = 0; m < 64; ++m) acc = fmaf(wp[m], t1s[rr][m], acc);
        bss[rr][q] = tanh2(acc);
    }
    __syncthreads();
    if (tid < 16) {
        float s = 0.f;
        for (int q = 0; q < 32; ++q) s += bss[tid][q];
        feat_sum[g * 16 + tid] = s;
    }
}

// ---------------------------------------------------------------------------
// shared neuron activation
// ---------------------------------------------------------------------------
__device__ __forceinline__ float actn(int n, float pre, float th) {
    if (n < O0)       return sigf(pre - th);
    else if (n < O1)  return tanh2(pre);
    else if (n < O2)  return fmaxf(pre - th, 0.f);
    else              return sigf(pre);
}

// ---------------------------------------------------------------------------
// K2: neuron activations + group means (R4 structure — precompute `no`)
// ---------------------------------------------------------------------------
__global__ __launch_bounds__(256) void neuron_kernel(
    const float* __restrict__ feat_sum, const float* __restrict__ a,
    const float* __restrict__ thr,
    float* __restrict__ no, float* __restrict__ means)
{
    const int b = blockIdx.x;
    const float s = feat_sum[b];
    float g0 = 0.f, g1 = 0.f, g2 = 0.f, g3 = 0.f;
    for (int n = threadIdx.x; n < NN; n += 256) {
        float v = actn(n, s * a[n], thr[n]);
        if (n < O0) g0 += v; else if (n < O1) g1 += v;
        else if (n < O2) g2 += v; else g3 += v;
        no[b * NN + n] = v;
    }
    __shared__ float red[4][256];
    red[0][threadIdx.x] = g0; red[1][threadIdx.x] = g1;
    red[2][threadIdx.x] = g2; red[3][threadIdx.x] = g3;
    __syncthreads();
    if (threadIdx.x < 4) {
        float acc = 0.f;
        for (int i = 0; i < 256; ++i) acc += red[threadIdx.x][i];
        const float inv[4] = {1.f/800.f, 1.f/700.f, 1.f/600.f, 1.f/400.f};
        means[b * 4 + threadIdx.x] = acc * inv[threadIdx.x];
    }
}

// ---------------------------------------------------------------------------
// K3: h1 = relu(no @ int_w1.T + int_b1)  M=512 N=256 K=2500 (R4 structure)
// ---------------------------------------------------------------------------
__global__ __launch_bounds__(256) void gemm_h1(
    const float* __restrict__ no,
    const float* __restrict__ int_w1,   // 256 x 2500
    const float* __restrict__ int_b1,
    float* __restrict__ h1)
{
    __shared__ float As[32][33];
    __shared__ float Bs[32][33];
    const int b0 = blockIdx.x * 32;
    const int m0 = blockIdx.y * 32;
    const int tid = threadIdx.x;
    const int ty = tid >> 4, tx = tid & 15;
    const int li = tid >> 3;
    const int lj = (tid & 7) * 4;

    float acc00 = 0.f, acc01 = 0.f, acc10 = 0.f, acc11 = 0.f;

    for (int k0 = 0; k0 < NN; k0 += 32) {
        float4 av = make_float4(0.f, 0.f, 0.f, 0.f);
        if (k0 + lj < NN)
            av = *(const float4*)(no + (b0 + li) * NN + k0 + lj);
        As[li][lj + 0] = av.x; As[li][lj + 1] = av.y;
        As[li][lj + 2] = av.z; As[li][lj + 3] = av.w;

        float4 wv = make_float4(0.f, 0.f, 0.f, 0.f);
        if (k0 + lj < NN)
            wv = *(const float4*)(int_w1 + (m0 + li) * NN + k0 + lj);
        Bs[lj + 0][li] = wv.x; Bs[lj + 1][li] = wv.y;
        Bs[lj + 2][li] = wv.z; Bs[lj + 3][li] = wv.w;
        __syncthreads();

#pragma unroll 8
        for (int kk = 0; kk < 32; ++kk) {
            float a0 = As[ty * 2][kk],  a1 = As[ty * 2 + 1][kk];
            float w0 = Bs[kk][tx * 2],  w1 = Bs[kk][tx * 2 + 1];
            acc00 += a0 * w0; acc01 += a0 * w1;
            acc10 += a1 * w0; acc11 += a1 * w1;
        }
        __syncthreads();
    }
    const int bi = b0 + ty * 2, mj = m0 + tx * 2;
    h1[bi * 256 + mj]           = fmaxf(acc00 + int_b1[mj], 0.f);
    h1[bi * 256 + mj + 1]       = fmaxf(acc01 + int_b1[mj + 1], 0.f);
    h1[(bi + 1) * 256 + mj]     = fmaxf(acc10 + int_b1[mj], 0.f);
    h1[(bi + 1) * 256 + mj + 1] = fmaxf(acc11 + int_b1[mj + 1], 0.f);
}

// ---------------------------------------------------------------------------
// K4: tail MLP + output assembly.  one wave per batch row.
// ---------------------------------------------------------------------------
__global__ __launch_bounds__(64) void tail_kernel(
    const float* __restrict__ h1,
    const float* __restrict__ int_w2, const float* __restrict__ int_b2,
    const float* __restrict__ int_w3, const float* __restrict__ int_b3,
    const float* __restrict__ tw, const float* __restrict__ tb,
    const float* __restrict__ pw, const float* __restrict__ pb,
    const float* __restrict__ kw, const float* __restrict__ kb,
    const float* __restrict__ vw, const float* __restrict__ vb,
    const float* __restrict__ cw, const float* __restrict__ cb,
    const float* __restrict__ means,
    float* __restrict__ out)
{
    const int b = blockIdx.x;
    const int lane = threadIdx.x;
    __shared__ float h2s[64];
    __shared__ float ints[32];
    __shared__ float outs[16];

    {
        float acc = int_b2[lane];
        const float* hp = h1 + b * 256;
        const float* wp = int_w2 + lane * 256;
        for (int m = 0; m < 256; ++m) acc += wp[m] * hp[m];
        h2s[lane] = fmaxf(acc, 0.f);
    }
    __syncthreads();
    if (lane < 32) {
        float acc = int_b3[lane];
        const float* wp = int_w3 + lane * 64;
        for (int m = 0; m < 64; ++m) acc += wp[m] * h2s[m];
        ints[lane] = tanh2(acc);
    }
    __syncthreads();
    if (lane < 15) {
        const float* wsel; float bsel;
        if (lane < 3)       { wsel = tw + lane * 32;       bsel = tb[lane]; }
        else if (lane < 9)  { wsel = pw + (lane - 3) * 32; bsel = pb[lane - 3]; }
        else if (lane < 13) { wsel = kw + (lane - 9) * 32; bsel = kb[lane - 9]; }
        else if (lane == 13){ wsel = vw;                   bsel = vb[0]; }
        else                { wsel = cw;                   bsel = cb[0]; }
        float acc = bsel;
        for (int q = 0; q < 32; ++q) acc += wsel[q] * ints[q];
        outs[lane] = acc;
    }
    __syncthreads();
    if (lane < 20) {
        float v;
        if (lane < 15)       v = outs[lane];
        else if (lane == 15) v = sigf(outs[14]);
        else                 v = means[b * 4 + (lane - 16)];
        out[b * 20 + lane] = v;
    }
}

// ---------------------------------------------------------------------------
extern "C" void kernel_launch(void* const* d_in, const int* in_sizes, int n_in,
                              void* d_out, int out_size, void* d_ws, size_t ws_size,
                              hipStream_t stream)
{
    const float* x      = (const float*)d_in[0];
    const float* W_ih0  = (const float*)d_in[1];
    const float* W_hh0  = (const float*)d_in[2];
    const float* b_ih0  = (const float*)d_in[3];
    const float* b_hh0  = (const float*)d_in[4];
    const float* W_ih1  = (const float*)d_in[5];
    const float* W_hh1  = (const float*)d_in[6];
    const float* b_ih1  = (const float*)d_in[7];
    const float* b_hh1  = (const float*)d_in[8];
    const float* fp_w1  = (const float*)d_in[9];
    const float* fp_b1  = (const float*)d_in[10];
    const float* fp_w2  = (const float*)d_in[11];
    const float* fp_b2  = (const float*)d_in[12];
    const float* conn_w = (const float*)d_in[13];
    const float* sens   = (const float*)d_in[14];
    const float* thr    = (const float*)d_in[15];
    const float* int_w1 = (const float*)d_in[16];
    const float* int_b1 = (const float*)d_in[17];
    const float* int_w2 = (const float*)d_in[18];
    const float* int_b2 = (const float*)d_in[19];
    const float* int_w3 = (const float*)d_in[20];
    const float* int_b3 = (const float*)d_in[21];
    const float* tw     = (const float*)d_in[22];
    const float* tb     = (const float*)d_in[23];
    const float* pw     = (const float*)d_in[24];
    const float* pb     = (const float*)d_in[25];
    const float* kw     = (const float*)d_in[26];
    const float* kb     = (const float*)d_in[27];
    const float* vw     = (const float*)d_in[28];
    const float* vb     = (const float*)d_in[29];
    const float* cw     = (const float*)d_in[30];
    const float* cb     = (const float*)d_in[31];
    // d_in[32] = conn_idx -- unused: acts is a feat_sum broadcast, so the
    // gather/einsum collapses to feat_sum[b] * rowsum(conn_w)[n].

    float* ws = (float*)d_ws;
    float* out = (float*)d_out;

    prep_kernel<<<(PREP_TOTAL + 255) / 256, 256, 0, stream>>>(
        W_ih0, W_hh0, b_ih0, b_hh0, W_ih1, W_hh1, b_ih1, b_hh1,
        conn_w, sens, ws);

    lstm_mfma<<<128, 512, 0, stream>>>(
        x, ws, fp_w1, fp_b1, fp_w2, fp_b2, ws + OFF_FS);

    neuron_kernel<<<NB, 256, 0, stream>>>(
        ws + OFF_FS, ws + OFF_A, thr, ws + OFF_NO, ws + OFF_MEANS);

    {
        dim3 grid(NB / 32, 256 / 32);
        gemm_h1<<<grid, 256, 0, stream>>>(
            ws + OFF_NO, int_w1, int_b1, ws + OFF_H1);
    }

    tail_kernel<<<NB, 64, 0, stream>>>(
        ws + OFF_H1, int_w2, int_b2, int_w3, int_b3,
        tw, tb, pw, pb, kw, kb, vw, vb, cw, cb,
        ws + OFF_MEANS, out);
}

// Round 12
// 437.075 us; speedup vs baseline: 9.8803x; 9.8803x over previous
//
#include <hip/hip_runtime.h>
#include <math.h>

// ---------------------------------------------------------------------------
// Sizes
// ---------------------------------------------------------------------------
#define NB   512
#define TT   60
#define FF   5
#define HH   128
#define G4   512
#define NN   2500
#define KK   50

#define O0 800
#define O1 1500
#define O2 2100

// ---------------------------------------------------------------------------
// Workspace layout (float offsets).
// B-fragment streams pre-swizzled into MFMA B-operand order (validated R6):
//   B-frag element: k = kb*32 + (l>>4)*8 + j ; n = g*128 + w*16 + (l&15)
// A-frag h layout (validated R6): addr = (k>>5)*512 + ((k>>3)&3)*128 + row*8 + (k&7)
// ---------------------------------------------------------------------------
#define OFF_B0F   0                        // 81920 halves = 40960 floats
#define OFF_B1F   40960                    // 131072 halves = 65536 floats
#define OFF_BIAS0 106496                   // 512
#define OFF_BIAS1 107008                   // 512
#define OFF_A     107520                   // 2500
#define OFF_FS    110020                   // 512
#define OFF_NO    110532                   // 512*2500
#define OFF_MEANS 1390532                  // 2048
#define OFF_H1    1392580                  // 512*256

#define P0 81920                           // end B0F (halves)
#define P1 212992                          // end B1F
#define P2 213504                          // end bias0
#define P3 214016                          // end bias1
#define PREP_TOTAL 216516                  // end a[n]

typedef _Float16 f16x8 __attribute__((ext_vector_type(8)));
typedef float f32x4 __attribute__((ext_vector_type(4)));

#define MFMA16(A, B, C) __builtin_amdgcn_mfma_f32_16x16x32_f16((A), (B), (C), 0, 0, 0)

__device__ __forceinline__ float sigf(float x) {
    return 1.0f / (1.0f + __expf(-x));
}
__device__ __forceinline__ float tanh2(float x) {
    float e = __expf(-2.0f * x);
    return fmaf(2.0f, 1.0f / (1.0f + e), -1.0f);
}

// ---------------------------------------------------------------------------
// K0: prep — B-frag swizzled fp16 weights, bias folds, a[n].
// (x A-frags built on the fly in K1 from an LDS stash.)
// ---------------------------------------------------------------------------
__global__ __launch_bounds__(256) void prep_kernel(
    const float* __restrict__ W_ih0, const float* __restrict__ W_hh0,
    const float* __restrict__ b_ih0, const float* __restrict__ b_hh0,
    const float* __restrict__ W_ih1, const float* __restrict__ W_hh1,
    const float* __restrict__ b_ih1, const float* __restrict__ b_hh1,
    const float* __restrict__ conn_w, const float* __restrict__ sens,
    float* __restrict__ ws)
{
    int i = blockIdx.x * 256 + threadIdx.x;
    if (i >= PREP_TOTAL) return;

    if (i < P0) {                          // layer-0 B frags (K=160 padded)
        int j = i & 7, l = (i >> 3) & 63;
        int rest = i >> 9;
        int g = rest & 3;
        int kbw = rest >> 2;
        int kb = kbw % 5, w = kbw / 5;
        int k = kb * 32 + (l >> 4) * 8 + j;
        int n = g * 128 + w * 16 + (l & 15);
        float val = 0.f;
        if (k < 128)       val = W_hh0[n * HH + k];
        else if (k < 133)  val = W_ih0[n * FF + (k - 128)];
        ((_Float16*)(ws + OFF_B0F))[i] = (_Float16)val;
    } else if (i < P1) {                   // layer-1 B frags (K=256: Wih1|Whh1)
        int v = i - P0;
        int j = v & 7, l = (v >> 3) & 63;
        int rest = v >> 9;
        int g = rest & 3;
        int kb = (rest >> 2) & 7;
        int w = rest >> 5;
        int k = kb * 32 + (l >> 4) * 8 + j;
        int n = g * 128 + w * 16 + (l & 15);
        float val = (k < 128) ? W_ih1[n * HH + k] : W_hh1[n * HH + (k - 128)];
        ((_Float16*)(ws + OFF_B1F))[v] = (_Float16)val;
    } else if (i < P2) {
        int j = i - P1;
        ws[OFF_BIAS0 + j] = b_ih0[j] + b_hh0[j];
    } else if (i < P3) {
        int j = i - P2;
        ws[OFF_BIAS1 + j] = b_ih1[j] + b_hh1[j];
    } else {
        int n = i - P3;
        float s = 0.f;
        const float* cw = conn_w + n * KK;
        for (int k = 0; k < KK; ++k) s += cw[k];
        ws[OFF_A + n] = s * sens[n];
    }
}

// ---------------------------------------------------------------------------
// K1: MFMA 2-layer LSTM + feature head.
// 32 blocks x 512 threads (8 waves), block owns 16 batch rows.
// R12 = R6's verified streaming body VERBATIM (single h buffer, 4 barriers/
// step, compiler-scheduled weight loads — the proven 259 µs structure)
//   + bias folded into MFMA C-init
//   + x A-frag built in-register from LDS stash (XA prep stream deleted).
// ---------------------------------------------------------------------------
__global__ __launch_bounds__(512) void lstm_mfma(
    const float* __restrict__ x,
    const float* __restrict__ ws_ro,
    const float* __restrict__ fp_w1, const float* __restrict__ fp_b1,
    const float* __restrict__ fp_w2, const float* __restrict__ fp_b2,
    float* __restrict__ feat_sum)
{
    __shared__ __align__(16) _Float16 hcat[8 * 512];   // 8KB, single buffer
    __shared__ _Float16 xsh[16][304];                  // x stash
    __shared__ float t1s[16][65];
    __shared__ float bss[16][33];

    const int tid = threadIdx.x;
    const int w = tid >> 6, l = tid & 63;
    const int u = w * 16 + (l & 15);
    const int row0 = (l >> 4) * 4;
    const int bb = blockIdx.x;

    // zero h state (4096 halves = 512 x 16B)
    ((uint4*)hcat)[tid] = make_uint4(0u, 0u, 0u, 0u);

    // stage this block's 16 x-rows into LDS as fp16
    for (int i = tid; i < 16 * TT * FF; i += 512) {
        int r = i / (TT * FF), c = i % (TT * FF);
        xsh[r][c] = (_Float16)x[(bb * 16 + r) * (TT * FF) + c];
    }

    float bia0[4], bia1[4];
#pragma unroll
    for (int g = 0; g < 4; ++g) {
        bia0[g] = ws_ro[OFF_BIAS0 + g * 128 + u];
        bia1[g] = ws_ro[OFF_BIAS1 + g * 128 + u];
    }
    float c0[4] = {0.f, 0.f, 0.f, 0.f};
    float c1[4] = {0.f, 0.f, 0.f, 0.f};

    const f16x8* B0 = (const f16x8*)(ws_ro + OFF_B0F) + w * 20 * 64 + l;
    const f16x8* B1 = (const f16x8*)(ws_ro + OFF_B1F) + w * 32 * 64 + l;
    const f16x8* HF = (const f16x8*)hcat;

    // h write base (halves): element (row,k): (k>>5)*512 + ((k>>3)&3)*128 + row*8 + (k&7)
    const int h0base = (u >> 5) * 512 + ((u >> 3) & 3) * 128 + (u & 7);
    const int h1base = h0base + 2048;          // k = u+128

    __syncthreads();

    for (int t = 0; t < TT; ++t) {
        // build x A-frag: k = 128 + (l>>4)*8 + j -> nonzero only l<16, j<5
        f16x8 xaf = {(_Float16)0, (_Float16)0, (_Float16)0, (_Float16)0,
                     (_Float16)0, (_Float16)0, (_Float16)0, (_Float16)0};
        if (l < 16) {
            const _Float16* xr = &xsh[l][t * FF];
            xaf[0] = xr[0]; xaf[1] = xr[1]; xaf[2] = xr[2];
            xaf[3] = xr[3]; xaf[4] = xr[4];
        }

        // ---------- layer 0: gates = [h0|x] @ B0  (K=160) ----------
        f32x4 a0 = {bia0[0], bia0[0], bia0[0], bia0[0]};
        f32x4 a1 = {bia0[1], bia0[1], bia0[1], bia0[1]};
        f32x4 a2 = {bia0[2], bia0[2], bia0[2], bia0[2]};
        f32x4 a3 = {bia0[3], bia0[3], bia0[3], bia0[3]};
#pragma unroll
        for (int kb = 0; kb < 4; ++kb) {
            f16x8 af = HF[kb * 64 + l];
            a0 = MFMA16(af, B0[(kb*4+0)*64], a0);
            a1 = MFMA16(af, B0[(kb*4+1)*64], a1);
            a2 = MFMA16(af, B0[(kb*4+2)*64], a2);
            a3 = MFMA16(af, B0[(kb*4+3)*64], a3);
        }
        a0 = MFMA16(xaf, B0[(16+0)*64], a0);
        a1 = MFMA16(xaf, B0[(16+1)*64], a1);
        a2 = MFMA16(xaf, B0[(16+2)*64], a2);
        a3 = MFMA16(xaf, B0[(16+3)*64], a3);

        float h0v[4];
#pragma unroll
        for (int r = 0; r < 4; ++r) {
            float gi = sigf(a0[r]);
            float gf = sigf(a1[r]);
            float gg = tanh2(a2[r]);
            float go = sigf(a3[r]);
            c0[r] = gf * c0[r] + gi * gg;
            h0v[r] = go * tanh2(c0[r]);
        }
        __syncthreads();                        // all reads of old h0 done
#pragma unroll
        for (int r = 0; r < 4; ++r)
            hcat[h0base + (row0 + r) * 8] = (_Float16)h0v[r];
        __syncthreads();                        // new h0 visible

        // ---------- layer 1: gates = [h0|h1] @ B1  (K=256) ----------
        f32x4 b0 = {bia1[0], bia1[0], bia1[0], bia1[0]};
        f32x4 b1 = {bia1[1], bia1[1], bia1[1], bia1[1]};
        f32x4 b2 = {bia1[2], bia1[2], bia1[2], bia1[2]};
        f32x4 b3 = {bia1[3], bia1[3], bia1[3], bia1[3]};
#pragma unroll
        for (int kb = 0; kb < 8; ++kb) {
            f16x8 af = HF[kb * 64 + l];
            b0 = MFMA16(af, B1[(kb*4+0)*64], b0);
            b1 = MFMA16(af, B1[(kb*4+1)*64], b1);
            b2 = MFMA16(af, B1[(kb*4+2)*64], b2);
            b3 = MFMA16(af, B1[(kb*4+3)*64], b3);
        }
        float h1v[4];
#pragma unroll
        for (int r = 0; r < 4; ++r) {
            float gi = sigf(b0[r]);
            float gf = sigf(b1[r]);
            float gg = tanh2(b2[r]);
            float go = sigf(b3[r]);
            c1[r] = gf * c1[r] + gi * gg;
            h1v[r] = go * tanh2(c1[r]);
        }
        __syncthreads();                        // all reads of old h1 done
#pragma unroll
        for (int r = 0; r < 4; ++r)
            hcat[h1base + (row0 + r) * 8] = (_Float16)h1v[r];
        __syncthreads();                        // new h1 visible
    }

    // ---------- head MLP on hlast = h1 (hcat kb4-7) ----------
    for (int idx = tid; idx < 16 * 64; idx += 512) {
        int r = idx >> 6, m = idx & 63;
        float acc = fp_b1[m];
        const float* wp = fp_w1 + m * HH;
        for (int k = 0; k < HH; ++k) {
            float hv = (float)hcat[2048 + (k >> 5) * 512 +
                                   (r + ((k >> 3) & 3) * 16) * 8 + (k & 7)];
            acc = fmaf(wp[k], hv, acc);
        }
        t1s[r][m] = fmaxf(acc, 0.f);
    }
    __syncthreads();
    if (tid < 16 * 32) {
        int r = tid >> 5, q = tid & 31;
        float acc = fp_b2[q];
        const float* wp = fp_w2 + q * 64;
        for (int m = 0; m < 64; ++m) acc = fmaf(wp[m], t1s[r][m], acc);
        bss[r][q] = tanh2(acc);
    }
    __syncthreads();
    if (tid < 16) {
        float s = 0.f;
        for (int q = 0; q < 32; ++q) s += bss[tid][q];
        feat_sum[bb * 16 + tid] = s;
    }
}

// ---------------------------------------------------------------------------
// shared neuron activation
// ---------------------------------------------------------------------------
__device__ __forceinline__ float actn(int n, float pre, float th) {
    if (n < O0)       return sigf(pre - th);
    else if (n < O1)  return tanh2(pre);
    else if (n < O2)  return fmaxf(pre - th, 0.f);
    else              return sigf(pre);
}

// ---------------------------------------------------------------------------
// K2: neuron activations + group means (R4 structure — precompute `no`)
// ---------------------------------------------------------------------------
__global__ __launch_bounds__(256) void neuron_kernel(
    const float* __restrict__ feat_sum, const float* __restrict__ a,
    const float* __restrict__ thr,
    float* __restrict__ no, float* __restrict__ means)
{
    const int b = blockIdx.x;
    const float s = feat_sum[b];
    float g0 = 0.f, g1 = 0.f, g2 = 0.f, g3 = 0.f;
    for (int n = threadIdx.x; n < NN; n += 256) {
        float v = actn(n, s * a[n], thr[n]);
        if (n < O0) g0 += v; else if (n < O1) g1 += v;
        else if (n < O2) g2 += v; else g3 += v;
        no[b * NN + n] = v;
    }
    __shared__ float red[4][256];
    red[0][threadIdx.x] = g0; red[1][threadIdx.x] = g1;
    red[2][threadIdx.x] = g2; red[3][threadIdx.x] = g3;
    __syncthreads();
    if (threadIdx.x < 4) {
        float acc = 0.f;
        for (int i = 0; i < 256; ++i) acc += red[threadIdx.x][i];
        const float inv[4] = {1.f/800.f, 1.f/700.f, 1.f/600.f, 1.f/400.f};
        means[b * 4 + threadIdx.x] = acc * inv[threadIdx.x];
    }
}

// ---------------------------------------------------------------------------
// K3: h1 = relu(no @ int_w1.T + int_b1)  M=512 N=256 K=2500 (R4 structure)
// ---------------------------------------------------------------------------
__global__ __launch_bounds__(256) void gemm_h1(
    const float* __restrict__ no,
    const float* __restrict__ int_w1,   // 256 x 2500
    const float* __restrict__ int_b1,
    float* __restrict__ h1)
{
    __shared__ float As[32][33];
    __shared__ float Bs[32][33];
    const int b0 = blockIdx.x * 32;
    const int m0 = blockIdx.y * 32;
    const int tid = threadIdx.x;
    const int ty = tid >> 4, tx = tid & 15;
    const int li = tid >> 3;
    const int lj = (tid & 7) * 4;

    float acc00 = 0.f, acc01 = 0.f, acc10 = 0.f, acc11 = 0.f;

    for (int k0 = 0; k0 < NN; k0 += 32) {
        float4 av = make_float4(0.f, 0.f, 0.f, 0.f);
        if (k0 + lj < NN)
            av = *(const float4*)(no + (b0 + li) * NN + k0 + lj);
        As[li][lj + 0] = av.x; As[li][lj + 1] = av.y;
        As[li][lj + 2] = av.z; As[li][lj + 3] = av.w;

        float4 wv = make_float4(0.f, 0.f, 0.f, 0.f);
        if (k0 + lj < NN)
            wv = *(const float4*)(int_w1 + (m0 + li) * NN + k0 + lj);
        Bs[lj + 0][li] = wv.x; Bs[lj + 1][li] = wv.y;
        Bs[lj + 2][li] = wv.z; Bs[lj + 3][li] = wv.w;
        __syncthreads();

#pragma unroll 8
        for (int kk = 0; kk < 32; ++kk) {
            float a0 = As[ty * 2][kk],  a1 = As[ty * 2 + 1][kk];
            float w0 = Bs[kk][tx * 2],  w1 = Bs[kk][tx * 2 + 1];
            acc00 += a0 * w0; acc01 += a0 * w1;
            acc10 += a1 * w0; acc11 += a1 * w1;
        }
        __syncthreads();
    }
    const int bi = b0 + ty * 2, mj = m0 + tx * 2;
    h1[bi * 256 + mj]           = fmaxf(acc00 + int_b1[mj], 0.f);
    h1[bi * 256 + mj + 1]       = fmaxf(acc01 + int_b1[mj + 1], 0.f);
    h1[(bi + 1) * 256 + mj]     = fmaxf(acc10 + int_b1[mj], 0.f);
    h1[(bi + 1) * 256 + mj + 1] = fmaxf(acc11 + int_b1[mj + 1], 0.f);
}

// ---------------------------------------------------------------------------
// K4: tail MLP + output assembly.  one wave per batch row. (R4 structure)
// ---------------------------------------------------------------------------
__global__ __launch_bounds__(64) void tail_kernel(
    const float* __restrict__ h1,
    const float* __restrict__ int_w2, const float* __restrict__ int_b2,
    const float* __restrict__ int_w3, const float* __restrict__ int_b3,
    const float* __restrict__ tw, const float* __restrict__ tb,
    const float* __restrict__ pw, const float* __restrict__ pb,
    const float* __restrict__ kw, const float* __restrict__ kb,
    const float* __restrict__ vw, const float* __restrict__ vb,
    const float* __restrict__ cw, const float* __restrict__ cb,
    const float* __restrict__ means,
    float* __restrict__ out)
{
    const int b = blockIdx.x;
    const int lane = threadIdx.x;
    __shared__ float h2s[64];
    __shared__ float ints[32];
    __shared__ float outs[16];

    {
        float acc = int_b2[lane];
        const float* hp = h1 + b * 256;
        const float* wp = int_w2 + lane * 256;
        for (int m = 0; m < 256; ++m) acc += wp[m] * hp[m];
        h2s[lane] = fmaxf(acc, 0.f);
    }
    __syncthreads();
    if (lane < 32) {
        float acc = int_b3[lane];
        const float* wp = int_w3 + lane * 64;
        for (int m = 0; m < 64; ++m) acc += wp[m] * h2s[m];
        ints[lane] = tanh2(acc);
    }
    __syncthreads();
    if (lane < 15) {
        const float* wsel; float bsel;
        if (lane < 3)       { wsel = tw + lane * 32;       bsel = tb[lane]; }
        else if (lane < 9)  { wsel = pw + (lane - 3) * 32; bsel = pb[lane - 3]; }
        else if (lane < 13) { wsel = kw + (lane - 9) * 32; bsel = kb[lane - 9]; }
        else if (lane == 13){ wsel = vw;                   bsel = vb[0]; }
        else                { wsel = cw;                   bsel = cb[0]; }
        float acc = bsel;
        for (int q = 0; q < 32; ++q) acc += wsel[q] * ints[q];
        outs[lane] = acc;
    }
    __syncthreads();
    if (lane < 20) {
        float v;
        if (lane < 15)       v = outs[lane];
        else if (lane == 15) v = sigf(outs[14]);
        else                 v = means[b * 4 + (lane - 16)];
        out[b * 20 + lane] = v;
    }
}

// ---------------------------------------------------------------------------
extern "C" void kernel_launch(void* const* d_in, const int* in_sizes, int n_in,
                              void* d_out, int out_size, void* d_ws, size_t ws_size,
                              hipStream_t stream)
{
    const float* x      = (const float*)d_in[0];
    const float* W_ih0  = (const float*)d_in[1];
    const float* W_hh0  = (const float*)d_in[2];
    const float* b_ih0  = (const float*)d_in[3];
    const float* b_hh0  = (const float*)d_in[4];
    const float* W_ih1  = (const float*)d_in[5];
    const float* W_hh1  = (const float*)d_in[6];
    const float* b_ih1  = (const float*)d_in[7];
    const float* b_hh1  = (const float*)d_in[8];
    const float* fp_w1  = (const float*)d_in[9];
    const float* fp_b1  = (const float*)d_in[10];
    const float* fp_w2  = (const float*)d_in[11];
    const float* fp_b2  = (const float*)d_in[12];
    const float* conn_w = (const float*)d_in[13];
    const float* sens   = (const float*)d_in[14];
    const float* thr    = (const float*)d_in[15];
    const float* int_w1 = (const float*)d_in[16];
    const float* int_b1 = (const float*)d_in[17];
    const float* int_w2 = (const float*)d_in[18];
    const float* int_b2 = (const float*)d_in[19];
    const float* int_w3 = (const float*)d_in[20];
    const float* int_b3 = (const float*)d_in[21];
    const float* tw     = (const float*)d_in[22];
    const float* tb     = (const float*)d_in[23];
    const float* pw     = (const float*)d_in[24];
    const float* pb     = (const float*)d_in[25];
    const float* kw     = (const float*)d_in[26];
    const float* kb     = (const float*)d_in[27];
    const float* vw     = (const float*)d_in[28];
    const float* vb     = (const float*)d_in[29];
    const float* cw     = (const float*)d_in[30];
    const float* cb     = (const float*)d_in[31];
    // d_in[32] = conn_idx -- unused: acts is a feat_sum broadcast, so the
    // gather/einsum collapses to feat_sum[b] * rowsum(conn_w)[n].

    float* ws = (float*)d_ws;
    float* out = (float*)d_out;

    prep_kernel<<<(PREP_TOTAL + 255) / 256, 256, 0, stream>>>(
        W_ih0, W_hh0, b_ih0, b_hh0, W_ih1, W_hh1, b_ih1, b_hh1,
        conn_w, sens, ws);

    lstm_mfma<<<NB / 16, 512, 0, stream>>>(
        x, ws, fp_w1, fp_b1, fp_w2, fp_b2, ws + OFF_FS);

    neuron_kernel<<<NB, 256, 0, stream>>>(
        ws + OFF_FS, ws + OFF_A, thr, ws + OFF_NO, ws + OFF_MEANS);

    {
        dim3 grid(NB / 32, 256 / 32);
        gemm_h1<<<grid, 256, 0, stream>>>(
            ws + OFF_NO, int_w1, int_b1, ws + OFF_H1);
    }

    tail_kernel<<<NB, 64, 0, stream>>>(
        ws + OFF_H1, int_w2, int_b2, int_w3, int_b3,
        tw, tb, pw, pb, kw, kb, vw, vb, cw, cb,
        ws + OFF_MEANS, out);
}